// Round 15
// baseline (62.785 us; speedup 1.0000x reference)
//
#include <hip/hip_runtime.h>
#include <math.h>

#define T_ 10
#define D_ 8
#define B_ 32768
#define NSAMP (T_ * B_)   // 327680
#define HALF_ (NSAMP / 2) // 163840

#define DEV static __device__ __forceinline__

// ---------------------------------------------------------------------------
// Precompute (wave-uniform math):
//   WS[0..63]  : combined layer-0 gate U0_w = RZ*RY*RX per wire (8 floats/wire)
//   WS[64..95] : per wire w, B_w = Hadamard transform of A_w = U1_w† Z U1_w,
//                divided by 4: (B00, B11, BR, BI); B[1] = BR - i*BI.
// ---------------------------------------------------------------------------
__global__ void precompute_U(const float* __restrict__ params, float* __restrict__ WS) {
    int idx = threadIdx.x;
    if (idx >= 16) return;
    float ax = 0.5f*params[idx*3+0], ay = 0.5f*params[idx*3+1], az = 0.5f*params[idx*3+2];
    float cx = cosf(ax), sx = sinf(ax);
    float cy = cosf(ay), sy = sinf(ay);
    float cz = cosf(az), sz = sinf(az);
    // M = RY*RX
    float m00r = cy*cx, m00i = sy*sx;
    float m01r = -sy*cx, m01i = -cy*sx;
    float m10r = sy*cx,  m10i = -cy*sx;
    float m11r = cy*cx,  m11i = -sy*sx;
    // U = RZ*M
    float u00r = cz*m00r + sz*m00i, u00i = cz*m00i - sz*m00r;
    float u01r = cz*m01r + sz*m01i, u01i = cz*m01i - sz*m01r;
    float u10r = cz*m10r - sz*m10i, u10i = cz*m10i + sz*m10r;
    float u11r = cz*m11r - sz*m11i, u11i = cz*m11i + sz*m11r;
    if (idx < 8) {
        float* o = WS + idx*8;
        o[0]=u00r; o[1]=u00i; o[2]=u01r; o[3]=u01i;
        o[4]=u10r; o[5]=u10i; o[6]=u11r; o[7]=u11i;
    } else {
        // A = u† Z u (Hermitian): α=A00, δ=A11 real; β=A01.
        float al = u00r*u00r+u00i*u00i - (u10r*u10r+u10i*u10i);
        float de = u01r*u01r+u01i*u01i - (u11r*u11r+u11i*u11i);
        float br = u00r*u01r+u00i*u01i - (u10r*u11r+u10i*u11i);
        float bi = u00r*u01i-u00i*u01r - (u10r*u11i-u10i*u11r);
        float* o = WS + 64 + (idx-8)*4;
        o[0] = 0.25f*(al+de+2.f*br);
        o[1] = 0.25f*(al+de-2.f*br);
        o[2] = 0.25f*(al-de);
        o[3] = -0.5f*bi;
    }
}

// d-vector of chain site: d = (d0, m1, conj(m1), d3), m1 = mr + i*mi.
DEV void dsite(const float* __restrict__ u, float th,
               float& d0, float& d3, float& mr, float& mi) {
    asm volatile("" : "+v"(th));   // pin: don't hoist all sites' sin/cos together
    float c = __cosf(th), s = __sinf(th);
    float a0r = c*c, a0i = -c*s, a1r = c*s, a1i = s*s;
    float f0r = u[0]*a0r - u[1]*a0i + u[2]*a1r - u[3]*a1i;
    float f0i = u[0]*a0i + u[1]*a0r + u[2]*a1i + u[3]*a1r;
    float f1r = u[4]*a0r - u[5]*a0i + u[6]*a1r - u[7]*a1i;
    float f1i = u[4]*a0i + u[5]*a0r + u[6]*a1i + u[7]*a1r;
    float Dpr=f0r+f1r, Dpi=f0i+f1i, Dmr=f0r-f1r, Dmi=f0i-f1i;
    d0 = Dpr*Dpr + Dpi*Dpi;
    d3 = Dmr*Dmr + Dmi*Dmi;
    mr = Dpr*Dmr + Dpi*Dmi;
    mi = Dpi*Dmr - Dpr*Dmi;
}

// ---------------------------------------------------------------------------
// TWO samples per LANE (in-wave ILP): each lane runs two independent MPS
// chains (R13-proven symmetric 16-real representation), interleaved via
// unrolled j loops — every latency event (sincos, FMA chain, WS s_load)
// has a same-wave independent twin. All array indices compile-time (rule
// #20). __launch_bounds__(256) plain — R9/R14-proven natural allocation.
// ---------------------------------------------------------------------------
__global__ __launch_bounds__(256) void sim_kernel(const float* __restrict__ X,
                                                  const float* __restrict__ WS,
                                                  float* __restrict__ qf) {
    const int tid = blockIdx.x*256 + threadIdx.x;   // 0..HALF_-1

    float xr[2][8];
#pragma unroll
    for (int j = 0; j < 2; ++j) {
        const float* xp = X + (tid + j*HALF_)*8;
        float4 t0 = *(const float4*)xp; float4 t1 = *(const float4*)(xp+4);
        xr[j][0]=0.5f*t0.x; xr[j][1]=0.5f*t0.y; xr[j][2]=0.5f*t0.z; xr[j][3]=0.5f*t0.w;
        xr[j][4]=0.5f*t1.x; xr[j][5]=0.5f*t1.y; xr[j][6]=0.5f*t1.z; xr[j][7]=0.5f*t1.w;
    }

    const float B00 = WS[64], B11 = WS[65], BR0 = WS[66], BI0 = WS[67];

    float G00[2], G11[2], G01r[2], G01i[2];
#pragma unroll
    for (int j = 0; j < 2; ++j)
        dsite(WS, xr[j][0], G00[j], G11[j], G01r[j], G01i[j]);

    // suffix scalars
    float SR[2][6], ST[2][6];
#pragma unroll
    for (int j = 0; j < 2; ++j) {
        SR[j][5]=1.f; ST[j][5]=1.f;
        float a,b,r,i;
        dsite(WS+56, xr[j][7], a,b,r,i); SR[j][4]=0.5f*(a+b);          ST[j][4]=r;
        dsite(WS+48, xr[j][6], a,b,r,i); SR[j][3]=SR[j][4]*0.5f*(a+b); ST[j][3]=ST[j][4]*r;
        dsite(WS+40, xr[j][5], a,b,r,i); SR[j][2]=SR[j][3]*0.5f*(a+b); ST[j][2]=ST[j][3]*r;
        dsite(WS+32, xr[j][4], a,b,r,i); SR[j][1]=SR[j][2]*0.5f*(a+b); ST[j][1]=ST[j][2]*r;
        dsite(WS+24, xr[j][3], a,b,r,i); SR[j][0]=SR[j][1]*0.5f*(a+b); ST[j][0]=ST[j][1]*r;
    }

    // M-state, symmetric representation (16 reals per sample)
    float a0[2],a3[2],a1r[2],a1i[2], c0[2],c3[2],c1r[2],c1i[2],
          b0r[2],b0i[2],b1r[2],b1i[2],b2r[2],b2i[2],b3r[2],b3i[2];
    {
        const float C0n=WS[68], C3n=WS[69], CRn=WS[70], CIn=WS[71]; // B1 = CR - i*CI
#pragma unroll
        for (int j = 0; j < 2; ++j) {
            float D0,D3,Dmr,Dmi;
            dsite(WS+8, xr[j][1], D0,D3,Dmr,Dmi);
            a0[j] = D0*C0n;  a3[j] = D0*C3n;  a1r[j] = D0*CRn;  a1i[j] = -D0*CIn;
            c0[j] = D3*C3n;  c3[j] = D3*C0n;  c1r[j] = D3*CRn;  c1i[j] =  D3*CIn;
            b0r[j] = Dmr*CRn + Dmi*CIn;  b0i[j] = Dmi*CRn - Dmr*CIn;
            b1r[j] = Dmr*C0n;            b1i[j] = Dmi*C0n;
            b2r[j] = Dmr*C3n;            b2i[j] = Dmi*C3n;
            b3r[j] = Dmr*CRn - Dmi*CIn;  b3i[j] = Dmr*CIn + Dmi*CRn;
        }
    }

    float Ev[2][8];

#pragma unroll
    for (int wi = 1; wi <= 6; ++wi) {
        const float* Bp = WS + 64 + 4*(wi+1);
        const float C0n=Bp[0], C3n=Bp[1], CRn=Bp[2], CIn=Bp[3]; // C1 = CR - i*CI
#pragma unroll
        for (int j = 0; j < 2; ++j) {
            float d0,d3,mr,mi;
            dsite(WS + 8*(wi+1), xr[j][wi+1], d0,d3,mr,mi);

            // ---- closure: E_wi ----
            {
                float Q0 = a0[j]*G00[j] + c0[j]*G11[j] + 2.f*(b0r[j]*G01r[j] - b0i[j]*G01i[j]);
                float Q3 = a3[j]*G11[j] + c3[j]*G00[j] + 2.f*(b3r[j]*G01r[j] + b3i[j]*G01i[j]);
                float Q1r = a1r[j]*G01r[j] - a1i[j]*G01i[j] + b1r[j]*G00[j] + b2r[j]*G11[j] + c1r[j]*G01r[j] + c1i[j]*G01i[j];
                float Q1i = a1r[j]*G01i[j] + a1i[j]*G01r[j] + b1i[j]*G00[j] - b2i[j]*G11[j] + c1i[j]*G01r[j] - c1r[j]*G01i[j];
                float P0 = a0[j]*G11[j] + c0[j]*G00[j] + 2.f*(b0r[j]*G01r[j] + b0i[j]*G01i[j]);
                float P3 = a3[j]*G00[j] + c3[j]*G11[j] + 2.f*(b3r[j]*G01r[j] - b3i[j]*G01i[j]);
                float P1r = a1r[j]*G01r[j] + a1i[j]*G01i[j] + b1r[j]*G11[j] + b2r[j]*G00[j] + c1r[j]*G01r[j] - c1i[j]*G01i[j];
                float P1i = -a1r[j]*G01i[j] + a1i[j]*G01r[j] + b1i[j]*G11[j] - b2i[j]*G00[j] + c1i[j]*G01r[j] + c1r[j]*G01i[j];
                float S0 = 0.5f*(B00*Q0 + B11*P0);
                float S3 = 0.5f*(B11*Q3 + B00*P3);
                float S1r = 0.5f*(BR0*Q1r + BI0*Q1i + BR0*P1r - BI0*P1i);
                float S1i = 0.5f*(BR0*Q1i - BI0*Q1r + BR0*P1i + BI0*P1r);
                float eR = SR[j][wi-1], eT = ST[j][wi-1];
                float e1r = mr*eT, e1i = mi*eT;
                Ev[j][wi] = eR*(d0*S0 + d3*S3) + 2.f*(e1r*S1r - e1i*S1i);
            }

            // ---- update: M <- M · diag(d) · circ(C) ----
            {
                float n0 = a0[j]*d0, n3 = a3[j]*d3;
                float n1r = a1r[j]*mr - a1i[j]*mi, n1i = a1r[j]*mi + a1i[j]*mr;
                a0[j]  = n0*C0n + n3*C3n + 2.f*(n1r*CRn + n1i*CIn);
                a3[j]  = n0*C3n + n3*C0n + 2.f*(n1r*CRn - n1i*CIn);
                a1r[j] = (n0+n3)*CRn + n1r*(C0n+C3n);
                a1i[j] = (n3-n0)*CIn + n1i*(C0n-C3n);
                float p0 = c0[j]*d0, p3 = c3[j]*d3;
                float p1r = c1r[j]*mr - c1i[j]*mi, p1i = c1r[j]*mi + c1i[j]*mr;
                c0[j]  = p0*C0n + p3*C3n + 2.f*(p1r*CRn + p1i*CIn);
                c3[j]  = p0*C3n + p3*C0n + 2.f*(p1r*CRn - p1i*CIn);
                c1r[j] = (p0+p3)*CRn + p1r*(C0n+C3n);
                c1i[j] = (p3-p0)*CIn + p1i*(C0n-C3n);
                float q0r = b0r[j]*d0, q0i = b0i[j]*d0;
                float q1r = b1r[j]*mr - b1i[j]*mi, q1i = b1r[j]*mi + b1i[j]*mr;
                float q2r = b2r[j]*mr + b2i[j]*mi, q2i = b2i[j]*mr - b2r[j]*mi;
                float q3r = b3r[j]*d3, q3i = b3i[j]*d3;
                float nb0r = q0r*C0n + q1r*CRn + q1i*CIn + q2r*CRn - q2i*CIn + q3r*C3n;
                float nb0i = q0i*C0n + q1i*CRn - q1r*CIn + q2i*CRn + q2r*CIn + q3i*C3n;
                float nb1r = q0r*CRn + q0i*CIn + q1r*C0n + q2r*C3n + q3r*CRn - q3i*CIn;
                float nb1i = q0i*CRn - q0r*CIn + q1i*C0n + q2i*C3n + q3i*CRn + q3r*CIn;
                float nb2r = q0r*CRn - q0i*CIn + q1r*C3n + q2r*C0n + q3r*CRn + q3i*CIn;
                float nb2i = q0i*CRn + q0r*CIn + q1i*C3n + q2i*C0n + q3i*CRn - q3r*CIn;
                float nb3r = q0r*C3n + q1r*CRn - q1i*CIn + q2r*CRn + q2i*CIn + q3r*C0n;
                float nb3i = q0i*C3n + q1i*CRn + q1r*CIn + q2i*CRn - q2r*CIn + q3i*C0n;
                b0r[j]=nb0r; b0i[j]=nb0i; b1r[j]=nb1r; b1i[j]=nb1i;
                b2r[j]=nb2r; b2i[j]=nb2i; b3r[j]=nb3r; b3i[j]=nb3i;
            }
        }
    }

    // ---- final closures ----
#pragma unroll
    for (int j = 0; j < 2; ++j) {
        float Q0 = a0[j]*G00[j] + c0[j]*G11[j] + 2.f*(b0r[j]*G01r[j] - b0i[j]*G01i[j]);
        float Q3 = a3[j]*G11[j] + c3[j]*G00[j] + 2.f*(b3r[j]*G01r[j] + b3i[j]*G01i[j]);
        float Q1r = a1r[j]*G01r[j] - a1i[j]*G01i[j] + b1r[j]*G00[j] + b2r[j]*G11[j] + c1r[j]*G01r[j] + c1i[j]*G01i[j];
        float Q1i = a1r[j]*G01i[j] + a1i[j]*G01r[j] + b1i[j]*G00[j] - b2i[j]*G11[j] + c1i[j]*G01r[j] - c1r[j]*G01i[j];
        Ev[j][7] = B00*Q0 + B11*Q3 + 2.f*(BR0*Q1r + BI0*Q1i);
        Ev[j][0] = 0.5f*(Q0 + Q3);
    }

#pragma unroll
    for (int j = 0; j < 2; ++j) {
        const int n = tid + j*HALF_;
        const int t_ = n >> 15;          // n / B
        const int b_ = n & (B_-1);       // n % B
        float* o = qf + b_*(T_*D_) + t_*D_;
        float4 o0 = {Ev[j][0], Ev[j][1], Ev[j][2], Ev[j][3]};
        float4 o1 = {Ev[j][4], Ev[j][5], Ev[j][6], Ev[j][7]};
        *(float4*)o = o0;
        *(float4*)(o+4) = o1;
    }
}

// One wave64 per batch row: h = qf_row @ W1 + b1 ; LayerNorm ; ReLU ; sigmoid(h @ W2 + b2)
__global__ __launch_bounds__(256) void head_kernel(const float* __restrict__ qf,
                                                   const float* __restrict__ W1,
                                                   const float* __restrict__ b1v,
                                                   const float* __restrict__ gam,
                                                   const float* __restrict__ bet,
                                                   const float* __restrict__ W2,
                                                   const float* __restrict__ b2v,
                                                   float* __restrict__ score) {
    const int lane = threadIdx.x & 63;
    int b = (blockIdx.x << 2) + (threadIdx.x >> 6);
    b = __builtin_amdgcn_readfirstlane(b);
    const float* row = qf + b * (T_ * D_);
    float h = b1v[lane];
#pragma unroll
    for (int k4 = 0; k4 < (T_ * D_) / 4; ++k4) {
        float4 rv = *(const float4*)(row + 4*k4);
        h = fmaf(rv.x, W1[((4*k4+0) << 6) + lane], h);
        h = fmaf(rv.y, W1[((4*k4+1) << 6) + lane], h);
        h = fmaf(rv.z, W1[((4*k4+2) << 6) + lane], h);
        h = fmaf(rv.w, W1[((4*k4+3) << 6) + lane], h);
    }
    float t = h;
#pragma unroll
    for (int m = 1; m < 64; m <<= 1) t += __shfl_xor(t, m, 64);
    float mu = t * (1.0f / 64.0f);
    float d = h - mu;
    float vv = d * d;
#pragma unroll
    for (int m = 1; m < 64; m <<= 1) vv += __shfl_xor(vv, m, 64);
    float rs = rsqrtf(vv * (1.0f / 64.0f) + 1e-5f);
    float hn = fmaxf(d * rs * gam[lane] + bet[lane], 0.f);
    float sacc = hn * W2[lane];
#pragma unroll
    for (int m = 1; m < 64; m <<= 1) sacc += __shfl_xor(sacc, m, 64);
    if (lane == 0) score[b] = 1.0f / (1.0f + expf(-(sacc + b2v[0])));
}

extern "C" void kernel_launch(void* const* d_in, const int* in_sizes, int n_in,
                              void* d_out, int out_size, void* d_ws, size_t ws_size,
                              hipStream_t stream) {
    const float* X_seq  = (const float*)d_in[0];
    const float* params = (const float*)d_in[1];
    const float* W1     = (const float*)d_in[2];
    const float* b1v    = (const float*)d_in[3];
    const float* gam    = (const float*)d_in[4];
    const float* bet    = (const float*)d_in[5];
    const float* W2     = (const float*)d_in[6];
    const float* b2v    = (const float*)d_in[7];

    float* out   = (float*)d_out;
    float* score = out;          // B floats
    float* qf    = out + B_;     // B*T*D floats
    float* WS    = (float*)d_ws; // 96 floats

    hipLaunchKernelGGL(precompute_U, dim3(1), dim3(64), 0, stream, params, WS);
    hipLaunchKernelGGL(sim_kernel, dim3(HALF_ / 256), dim3(256), 0, stream, X_seq, WS, qf);
    hipLaunchKernelGGL(head_kernel, dim3(B_ / 4), dim3(256), 0, stream,
                       qf, W1, b1v, gam, bet, W2, b2v, score);
}

// Round 16
// 53.806 us; speedup vs baseline: 1.1669x; 1.1669x over previous
//
#include <hip/hip_runtime.h>
#include <math.h>

#define T_ 10
#define D_ 8
#define B_ 32768
#define NSAMP (T_ * B_)   // 327680

#define DEV static __device__ __forceinline__

// ---------------------------------------------------------------------------
// Precompute (wave-uniform math):
//   WS[0..63]  : combined layer-0 gate U0_w = RZ*RY*RX per wire (8 floats/wire)
//   WS[64..95] : per wire w, B_w = Hadamard transform of A_w = U1_w† Z U1_w,
//                divided by 4: (B00, B11, BR, BI); B[1] = BR - i*BI.
// ---------------------------------------------------------------------------
__global__ void precompute_U(const float* __restrict__ params, float* __restrict__ WS) {
    int idx = threadIdx.x;
    if (idx >= 16) return;
    float ax = 0.5f*params[idx*3+0], ay = 0.5f*params[idx*3+1], az = 0.5f*params[idx*3+2];
    float cx = cosf(ax), sx = sinf(ax);
    float cy = cosf(ay), sy = sinf(ay);
    float cz = cosf(az), sz = sinf(az);
    // M = RY*RX
    float m00r = cy*cx, m00i = sy*sx;
    float m01r = -sy*cx, m01i = -cy*sx;
    float m10r = sy*cx,  m10i = -cy*sx;
    float m11r = cy*cx,  m11i = -sy*sx;
    // U = RZ*M
    float u00r = cz*m00r + sz*m00i, u00i = cz*m00i - sz*m00r;
    float u01r = cz*m01r + sz*m01i, u01i = cz*m01i - sz*m01r;
    float u10r = cz*m10r - sz*m10i, u10i = cz*m10i + sz*m10r;
    float u11r = cz*m11r - sz*m11i, u11i = cz*m11i + sz*m11r;
    if (idx < 8) {
        float* o = WS + idx*8;
        o[0]=u00r; o[1]=u00i; o[2]=u01r; o[3]=u01i;
        o[4]=u10r; o[5]=u10i; o[6]=u11r; o[7]=u11i;
    } else {
        // A = u† Z u (Hermitian): α=A00, δ=A11 real; β=A01.
        float al = u00r*u00r+u00i*u00i - (u10r*u10r+u10i*u10i);
        float de = u01r*u01r+u01i*u01i - (u11r*u11r+u11i*u11i);
        float br = u00r*u01r+u00i*u01i - (u10r*u11r+u10i*u11i);
        float bi = u00r*u01i-u00i*u01r - (u10r*u11i-u10i*u11r);
        float* o = WS + 64 + (idx-8)*4;
        o[0] = 0.25f*(al+de+2.f*br);
        o[1] = 0.25f*(al+de-2.f*br);
        o[2] = 0.25f*(al-de);
        o[3] = -0.5f*bi;
    }
}

// d-vector of chain site: d = (d0, m1, conj(m1), d3), m1 = mr + i*mi.
DEV void dsite(const float* __restrict__ u, float th,
               float& d0, float& d3, float& mr, float& mi) {
    asm volatile("" : "+v"(th));   // pin: don't hoist all sites' sin/cos together
    float c = __cosf(th), s = __sinf(th);
    float a0r = c*c, a0i = -c*s, a1r = c*s, a1i = s*s;
    float f0r = u[0]*a0r - u[1]*a0i + u[2]*a1r - u[3]*a1i;
    float f0i = u[0]*a0i + u[1]*a0r + u[2]*a1i + u[3]*a1r;
    float f1r = u[4]*a0r - u[5]*a0i + u[6]*a1r - u[7]*a1i;
    float f1i = u[4]*a0i + u[5]*a0r + u[6]*a1i + u[7]*a1r;
    float Dpr=f0r+f1r, Dpi=f0i+f1i, Dmr=f0r-f1r, Dmi=f0i-f1i;
    d0 = Dpr*Dpr + Dpi*Dpi;
    d3 = Dmr*Dmr + Dmi*Dmi;
    mr = Dpr*Dmr + Dpi*Dmi;
    mi = Dpi*Dmr - Dpr*Dmi;
}

// ---------------------------------------------------------------------------
// One sample per LANE. MPS transfer-matrix contraction (R9/R12-proven math)
// with the chain's involution symmetry (R13-proven): sigma = (1<->2),
// M[r][c] = conj(M[sigma r][sigma c]). Independent state = 16 reals.
// __launch_bounds__(256) plain — R14-proven fastest configuration (53 µs).
// DO NOT: (256,K) caps (R10-R12: 130-270 MB scratch spill), no-attribute
// (R13: same), or 2-samples/lane ILP (R15: 2x state -> occupancy loss, +9µs).
// ---------------------------------------------------------------------------
__global__ __launch_bounds__(256) void sim_kernel(const float* __restrict__ X,
                                                  const float* __restrict__ WS,
                                                  float* __restrict__ qf) {
    const int n = blockIdx.x*256 + threadIdx.x;
    const float* xp = X + n*8;
    float xr[8];
    { float4 t0 = *(const float4*)xp; float4 t1 = *(const float4*)(xp+4);
      xr[0]=0.5f*t0.x; xr[1]=0.5f*t0.y; xr[2]=0.5f*t0.z; xr[3]=0.5f*t0.w;
      xr[4]=0.5f*t1.x; xr[5]=0.5f*t1.y; xr[6]=0.5f*t1.z; xr[7]=0.5f*t1.w; }

    const float B00 = WS[64], B11 = WS[65], BR0 = WS[66], BI0 = WS[67];

    // G = closure-site (wire 0) d-vector
    float G00, G11, G01r, G01i;
    dsite(WS, xr[0], G00, G11, G01r, G01i);

    // suffix scalars: SR[wi-1] = prod_{k=wi+2..7} rho_k, ST with tau
    float SR[6], ST[6];
    SR[5]=1.f; ST[5]=1.f;
    {
        float a,b,r,i;
        dsite(WS+56, xr[7], a,b,r,i); SR[4]=0.5f*(a+b);       ST[4]=r;
        dsite(WS+48, xr[6], a,b,r,i); SR[3]=SR[4]*0.5f*(a+b); ST[3]=ST[4]*r;
        dsite(WS+40, xr[5], a,b,r,i); SR[2]=SR[3]*0.5f*(a+b); ST[2]=ST[3]*r;
        dsite(WS+32, xr[4], a,b,r,i); SR[1]=SR[2]*0.5f*(a+b); ST[1]=ST[2]*r;
        dsite(WS+24, xr[3], a,b,r,i); SR[0]=SR[1]*0.5f*(a+b); ST[0]=ST[1]*r;
    }

    // ---- init: M = diag(d_1)·circ(B_1), symmetric representation ----
    float a0,a3,a1r,a1i, c0,c3,c1r,c1i, b0r,b0i,b1r,b1i,b2r,b2i,b3r,b3i;
    {
        float D0,D3,Dmr,Dmi;
        dsite(WS+8, xr[1], D0,D3,Dmr,Dmi);
        const float C0n=WS[68], C3n=WS[69], CRn=WS[70], CIn=WS[71]; // B1 = CR - i*CI
        a0 = D0*C0n;  a3 = D0*C3n;  a1r = D0*CRn;  a1i = -D0*CIn;
        c0 = D3*C3n;  c3 = D3*C0n;  c1r = D3*CRn;  c1i =  D3*CIn;
        b0r = Dmr*CRn + Dmi*CIn;  b0i = Dmi*CRn - Dmr*CIn;   // m1*C[1]
        b1r = Dmr*C0n;            b1i = Dmi*C0n;             // m1*C[0]
        b2r = Dmr*C3n;            b2i = Dmi*C3n;             // m1*C[3]
        b3r = Dmr*CRn - Dmi*CIn;  b3i = Dmr*CIn + Dmi*CRn;   // m1*conj(C[1])
    }

    float Ev[8];

#pragma unroll
    for (int wi = 1; wi <= 6; ++wi) {
        float d0,d3,mr,mi;
        dsite(WS + 8*(wi+1), xr[wi+1], d0,d3,mr,mi);  // site wi+1: closure e + update

        // ---- closure: E_wi (uses M = sites 1..wi) ----
        {
            float Q0 = a0*G00 + c0*G11 + 2.f*(b0r*G01r - b0i*G01i);
            float Q3 = a3*G11 + c3*G00 + 2.f*(b3r*G01r + b3i*G01i);
            float Q1r = a1r*G01r - a1i*G01i + b1r*G00 + b2r*G11 + c1r*G01r + c1i*G01i;
            float Q1i = a1r*G01i + a1i*G01r + b1i*G00 - b2i*G11 + c1i*G01r - c1r*G01i;
            float P0 = a0*G11 + c0*G00 + 2.f*(b0r*G01r + b0i*G01i);
            float P3 = a3*G00 + c3*G11 + 2.f*(b3r*G01r - b3i*G01i);
            float P1r = a1r*G01r + a1i*G01i + b1r*G11 + b2r*G00 + c1r*G01r - c1i*G01i;
            float P1i = -a1r*G01i + a1i*G01r + b1i*G11 - b2i*G00 + c1i*G01r + c1r*G01i;
            float S0 = 0.5f*(B00*Q0 + B11*P0);
            float S3 = 0.5f*(B11*Q3 + B00*P3);
            float S1r = 0.5f*(BR0*Q1r + BI0*Q1i + BR0*P1r - BI0*P1i);
            float S1i = 0.5f*(BR0*Q1i - BI0*Q1r + BR0*P1i + BI0*P1r);
            float eR = SR[wi-1], eT = ST[wi-1];
            float e1r = mr*eT, e1i = mi*eT;
            Ev[wi] = eR*(d0*S0 + d3*S3) + 2.f*(e1r*S1r - e1i*S1i);
        }

        // ---- update: M <- M · diag(d_{wi+1}) · circ(B_{wi+1}) ----
        {
            const float* Bp = WS + 64 + 4*(wi+1);
            const float C0n=Bp[0], C3n=Bp[1], CRn=Bp[2], CIn=Bp[3]; // C1 = CR - i*CI
            // row 0
            float n0 = a0*d0, n3 = a3*d3;
            float n1r = a1r*mr - a1i*mi, n1i = a1r*mi + a1i*mr;
            a0  = n0*C0n + n3*C3n + 2.f*(n1r*CRn + n1i*CIn);
            a3  = n0*C3n + n3*C0n + 2.f*(n1r*CRn - n1i*CIn);
            a1r = (n0+n3)*CRn + n1r*(C0n+C3n);
            a1i = (n3-n0)*CIn + n1i*(C0n-C3n);
            // row 3
            float p0 = c0*d0, p3 = c3*d3;
            float p1r = c1r*mr - c1i*mi, p1i = c1r*mi + c1i*mr;
            c0  = p0*C0n + p3*C3n + 2.f*(p1r*CRn + p1i*CIn);
            c3  = p0*C3n + p3*C0n + 2.f*(p1r*CRn - p1i*CIn);
            c1r = (p0+p3)*CRn + p1r*(C0n+C3n);
            c1i = (p3-p0)*CIn + p1i*(C0n-C3n);
            // row 1
            float q0r = b0r*d0, q0i = b0i*d0;
            float q1r = b1r*mr - b1i*mi, q1i = b1r*mi + b1i*mr;
            float q2r = b2r*mr + b2i*mi, q2i = b2i*mr - b2r*mi;
            float q3r = b3r*d3, q3i = b3i*d3;
            float nb0r = q0r*C0n + q1r*CRn + q1i*CIn + q2r*CRn - q2i*CIn + q3r*C3n;
            float nb0i = q0i*C0n + q1i*CRn - q1r*CIn + q2i*CRn + q2r*CIn + q3i*C3n;
            float nb1r = q0r*CRn + q0i*CIn + q1r*C0n + q2r*C3n + q3r*CRn - q3i*CIn;
            float nb1i = q0i*CRn - q0r*CIn + q1i*C0n + q2i*C3n + q3i*CRn + q3r*CIn;
            float nb2r = q0r*CRn - q0i*CIn + q1r*C3n + q2r*C0n + q3r*CRn + q3i*CIn;
            float nb2i = q0i*CRn + q0r*CIn + q1i*C3n + q2i*C0n + q3i*CRn - q3r*CIn;
            float nb3r = q0r*C3n + q1r*CRn - q1i*CIn + q2r*CRn + q2i*CIn + q3r*C0n;
            float nb3i = q0i*C3n + q1i*CRn + q1r*CIn + q2i*CRn - q2r*CIn + q3i*C0n;
            b0r=nb0r; b0i=nb0i; b1r=nb1r; b1i=nb1i;
            b2r=nb2r; b2i=nb2i; b3r=nb3r; b3i=nb3i;
        }
    }

    // ---- final closures from M = sites 1..7 ----
    {
        float Q0 = a0*G00 + c0*G11 + 2.f*(b0r*G01r - b0i*G01i);
        float Q3 = a3*G11 + c3*G00 + 2.f*(b3r*G01r + b3i*G01i);
        float Q1r = a1r*G01r - a1i*G01i + b1r*G00 + b2r*G11 + c1r*G01r + c1i*G01i;
        float Q1i = a1r*G01i + a1i*G01r + b1i*G00 - b2i*G11 + c1i*G01r - c1r*G01i;
        Ev[7] = B00*Q0 + B11*Q3 + 2.f*(BR0*Q1r + BI0*Q1i);
        Ev[0] = 0.5f*(Q0 + Q3);
    }

    const int t_ = n >> 15;          // n / B
    const int b_ = n & (B_-1);       // n % B
    float* o = qf + b_*(T_*D_) + t_*D_;
    float4 o0 = {Ev[0], Ev[1], Ev[2], Ev[3]};
    float4 o1 = {Ev[4], Ev[5], Ev[6], Ev[7]};
    *(float4*)o = o0;
    *(float4*)(o+4) = o1;
}

// One wave64 per batch row: h = qf_row @ W1 + b1 ; LayerNorm ; ReLU ; sigmoid(h @ W2 + b2)
__global__ __launch_bounds__(256) void head_kernel(const float* __restrict__ qf,
                                                   const float* __restrict__ W1,
                                                   const float* __restrict__ b1v,
                                                   const float* __restrict__ gam,
                                                   const float* __restrict__ bet,
                                                   const float* __restrict__ W2,
                                                   const float* __restrict__ b2v,
                                                   float* __restrict__ score) {
    const int lane = threadIdx.x & 63;
    int b = (blockIdx.x << 2) + (threadIdx.x >> 6);
    b = __builtin_amdgcn_readfirstlane(b);
    const float* row = qf + b * (T_ * D_);
    float h = b1v[lane];
#pragma unroll
    for (int k4 = 0; k4 < (T_ * D_) / 4; ++k4) {
        float4 rv = *(const float4*)(row + 4*k4);
        h = fmaf(rv.x, W1[((4*k4+0) << 6) + lane], h);
        h = fmaf(rv.y, W1[((4*k4+1) << 6) + lane], h);
        h = fmaf(rv.z, W1[((4*k4+2) << 6) + lane], h);
        h = fmaf(rv.w, W1[((4*k4+3) << 6) + lane], h);
    }
    float t = h;
#pragma unroll
    for (int m = 1; m < 64; m <<= 1) t += __shfl_xor(t, m, 64);
    float mu = t * (1.0f / 64.0f);
    float d = h - mu;
    float vv = d * d;
#pragma unroll
    for (int m = 1; m < 64; m <<= 1) vv += __shfl_xor(vv, m, 64);
    float rs = rsqrtf(vv * (1.0f / 64.0f) + 1e-5f);
    float hn = fmaxf(d * rs * gam[lane] + bet[lane], 0.f);
    float sacc = hn * W2[lane];
#pragma unroll
    for (int m = 1; m < 64; m <<= 1) sacc += __shfl_xor(sacc, m, 64);
    if (lane == 0) score[b] = 1.0f / (1.0f + expf(-(sacc + b2v[0])));
}

extern "C" void kernel_launch(void* const* d_in, const int* in_sizes, int n_in,
                              void* d_out, int out_size, void* d_ws, size_t ws_size,
                              hipStream_t stream) {
    const float* X_seq  = (const float*)d_in[0];
    const float* params = (const float*)d_in[1];
    const float* W1     = (const float*)d_in[2];
    const float* b1v    = (const float*)d_in[3];
    const float* gam    = (const float*)d_in[4];
    const float* bet    = (const float*)d_in[5];
    const float* W2     = (const float*)d_in[6];
    const float* b2v    = (const float*)d_in[7];

    float* out   = (float*)d_out;
    float* score = out;          // B floats
    float* qf    = out + B_;     // B*T*D floats
    float* WS    = (float*)d_ws; // 96 floats

    hipLaunchKernelGGL(precompute_U, dim3(1), dim3(64), 0, stream, params, WS);
    hipLaunchKernelGGL(sim_kernel, dim3(NSAMP / 256), dim3(256), 0, stream, X_seq, WS, qf);
    hipLaunchKernelGGL(head_kernel, dim3(B_ / 4), dim3(256), 0, stream,
                       qf, W1, b1v, gam, bet, W2, b2v, score);
}

// Round 17
// 53.480 us; speedup vs baseline: 1.1740x; 1.0061x over previous
//
#include <hip/hip_runtime.h>
#include <math.h>

#define T_ 10
#define D_ 8
#define B_ 32768
#define NSAMP (T_ * B_)   // 327680

#define DEV static __device__ __forceinline__

// ---------------------------------------------------------------------------
// Precompute (wave-uniform math):
//   WS[0..63]  : combined layer-0 gate U0_w = RZ*RY*RX per wire (8 floats/wire)
//   WS[64..95] : per wire w, B_w = Hadamard transform of A_w = U1_w† Z U1_w,
//                divided by 4: (B00, B11, BR, BI); B[1] = BR - i*BI.
// ---------------------------------------------------------------------------
__global__ void precompute_U(const float* __restrict__ params, float* __restrict__ WS) {
    int idx = threadIdx.x;
    if (idx >= 16) return;
    float ax = 0.5f*params[idx*3+0], ay = 0.5f*params[idx*3+1], az = 0.5f*params[idx*3+2];
    float cx = cosf(ax), sx = sinf(ax);
    float cy = cosf(ay), sy = sinf(ay);
    float cz = cosf(az), sz = sinf(az);
    // M = RY*RX
    float m00r = cy*cx, m00i = sy*sx;
    float m01r = -sy*cx, m01i = -cy*sx;
    float m10r = sy*cx,  m10i = -cy*sx;
    float m11r = cy*cx,  m11i = -sy*sx;
    // U = RZ*M
    float u00r = cz*m00r + sz*m00i, u00i = cz*m00i - sz*m00r;
    float u01r = cz*m01r + sz*m01i, u01i = cz*m01i - sz*m01r;
    float u10r = cz*m10r - sz*m10i, u10i = cz*m10i + sz*m10r;
    float u11r = cz*m11r - sz*m11i, u11i = cz*m11i + sz*m11r;
    if (idx < 8) {
        float* o = WS + idx*8;
        o[0]=u00r; o[1]=u00i; o[2]=u01r; o[3]=u01i;
        o[4]=u10r; o[5]=u10i; o[6]=u11r; o[7]=u11i;
    } else {
        // A = u† Z u (Hermitian): α=A00, δ=A11 real; β=A01.
        float al = u00r*u00r+u00i*u00i - (u10r*u10r+u10i*u10i);
        float de = u01r*u01r+u01i*u01i - (u11r*u11r+u11i*u11i);
        float br = u00r*u01r+u00i*u01i - (u10r*u11r+u10i*u11i);
        float bi = u00r*u01i-u00i*u01r - (u10r*u11i-u10i*u11r);
        float* o = WS + 64 + (idx-8)*4;
        o[0] = 0.25f*(al+de+2.f*br);
        o[1] = 0.25f*(al+de-2.f*br);
        o[2] = 0.25f*(al-de);
        o[3] = -0.5f*bi;
    }
}

// d-vector of chain site: d = (d0, m1, conj(m1), d3), m1 = mr + i*mi.
DEV void dsite(const float* __restrict__ u, float th,
               float& d0, float& d3, float& mr, float& mi) {
    asm volatile("" : "+v"(th));   // pin: don't hoist all sites' sin/cos together
    float c = __cosf(th), s = __sinf(th);
    float a0r = c*c, a0i = -c*s, a1r = c*s, a1i = s*s;
    float f0r = u[0]*a0r - u[1]*a0i + u[2]*a1r - u[3]*a1i;
    float f0i = u[0]*a0i + u[1]*a0r + u[2]*a1i + u[3]*a1r;
    float f1r = u[4]*a0r - u[5]*a0i + u[6]*a1r - u[7]*a1i;
    float f1i = u[4]*a0i + u[5]*a0r + u[6]*a1i + u[7]*a1r;
    float Dpr=f0r+f1r, Dpi=f0i+f1i, Dmr=f0r-f1r, Dmi=f0i-f1i;
    d0 = Dpr*Dpr + Dpi*Dpi;
    d3 = Dmr*Dmr + Dmi*Dmi;
    mr = Dpr*Dmr + Dpi*Dmi;
    mi = Dpi*Dmr - Dpr*Dmi;
}

// ---------------------------------------------------------------------------
// One sample per LANE. MPS transfer-matrix contraction (R9/R12-proven math)
// with the chain's involution symmetry (R13-proven). 16-real M state.
// __launch_bounds__(256) plain — R14/R16-proven fastest configuration.
// R17 change: STREAM Ev[wi] to global as computed (frees ~6-8 loop-carried
// VGPRs, overlaps stores with compute). Same write traffic (L2 merges).
// DO NOT: (256,K) caps (R10-R12 spill), no-attribute (R13 spill),
// 2-samples/lane ILP (R15: +9µs).
// ---------------------------------------------------------------------------
__global__ __launch_bounds__(256) void sim_kernel(const float* __restrict__ X,
                                                  const float* __restrict__ WS,
                                                  float* __restrict__ qf) {
    const int n = blockIdx.x*256 + threadIdx.x;
    const float* xp = X + n*8;
    float xr[8];
    { float4 t0 = *(const float4*)xp; float4 t1 = *(const float4*)(xp+4);
      xr[0]=0.5f*t0.x; xr[1]=0.5f*t0.y; xr[2]=0.5f*t0.z; xr[3]=0.5f*t0.w;
      xr[4]=0.5f*t1.x; xr[5]=0.5f*t1.y; xr[6]=0.5f*t1.z; xr[7]=0.5f*t1.w; }

    const int t_ = n >> 15;          // n / B
    const int b_ = n & (B_-1);       // n % B
    float* o = qf + b_*(T_*D_) + t_*D_;

    const float B00 = WS[64], B11 = WS[65], BR0 = WS[66], BI0 = WS[67];

    // G = closure-site (wire 0) d-vector
    float G00, G11, G01r, G01i;
    dsite(WS, xr[0], G00, G11, G01r, G01i);

    // suffix scalars: SR[wi-1] = prod_{k=wi+2..7} rho_k, ST with tau
    float SR[6], ST[6];
    SR[5]=1.f; ST[5]=1.f;
    {
        float a,b,r,i;
        dsite(WS+56, xr[7], a,b,r,i); SR[4]=0.5f*(a+b);       ST[4]=r;
        dsite(WS+48, xr[6], a,b,r,i); SR[3]=SR[4]*0.5f*(a+b); ST[3]=ST[4]*r;
        dsite(WS+40, xr[5], a,b,r,i); SR[2]=SR[3]*0.5f*(a+b); ST[2]=ST[3]*r;
        dsite(WS+32, xr[4], a,b,r,i); SR[1]=SR[2]*0.5f*(a+b); ST[1]=ST[2]*r;
        dsite(WS+24, xr[3], a,b,r,i); SR[0]=SR[1]*0.5f*(a+b); ST[0]=ST[1]*r;
    }

    // ---- init: M = diag(d_1)·circ(B_1), symmetric representation ----
    float a0,a3,a1r,a1i, c0,c3,c1r,c1i, b0r,b0i,b1r,b1i,b2r,b2i,b3r,b3i;
    {
        float D0,D3,Dmr,Dmi;
        dsite(WS+8, xr[1], D0,D3,Dmr,Dmi);
        const float C0n=WS[68], C3n=WS[69], CRn=WS[70], CIn=WS[71]; // B1 = CR - i*CI
        a0 = D0*C0n;  a3 = D0*C3n;  a1r = D0*CRn;  a1i = -D0*CIn;
        c0 = D3*C3n;  c3 = D3*C0n;  c1r = D3*CRn;  c1i =  D3*CIn;
        b0r = Dmr*CRn + Dmi*CIn;  b0i = Dmi*CRn - Dmr*CIn;   // m1*C[1]
        b1r = Dmr*C0n;            b1i = Dmi*C0n;             // m1*C[0]
        b2r = Dmr*C3n;            b2i = Dmi*C3n;             // m1*C[3]
        b3r = Dmr*CRn - Dmi*CIn;  b3i = Dmr*CIn + Dmi*CRn;   // m1*conj(C[1])
    }

#pragma unroll
    for (int wi = 1; wi <= 6; ++wi) {
        float d0,d3,mr,mi;
        dsite(WS + 8*(wi+1), xr[wi+1], d0,d3,mr,mi);  // site wi+1: closure e + update

        // ---- closure: E_wi (uses M = sites 1..wi), streamed to global ----
        {
            float Q0 = a0*G00 + c0*G11 + 2.f*(b0r*G01r - b0i*G01i);
            float Q3 = a3*G11 + c3*G00 + 2.f*(b3r*G01r + b3i*G01i);
            float Q1r = a1r*G01r - a1i*G01i + b1r*G00 + b2r*G11 + c1r*G01r + c1i*G01i;
            float Q1i = a1r*G01i + a1i*G01r + b1i*G00 - b2i*G11 + c1i*G01r - c1r*G01i;
            float P0 = a0*G11 + c0*G00 + 2.f*(b0r*G01r + b0i*G01i);
            float P3 = a3*G00 + c3*G11 + 2.f*(b3r*G01r - b3i*G01i);
            float P1r = a1r*G01r + a1i*G01i + b1r*G11 + b2r*G00 + c1r*G01r - c1i*G01i;
            float P1i = -a1r*G01i + a1i*G01r + b1i*G11 - b2i*G00 + c1i*G01r + c1r*G01i;
            float S0 = 0.5f*(B00*Q0 + B11*P0);
            float S3 = 0.5f*(B11*Q3 + B00*P3);
            float S1r = 0.5f*(BR0*Q1r + BI0*Q1i + BR0*P1r - BI0*P1i);
            float S1i = 0.5f*(BR0*Q1i - BI0*Q1r + BR0*P1i + BI0*P1r);
            float eR = SR[wi-1], eT = ST[wi-1];
            float e1r = mr*eT, e1i = mi*eT;
            o[wi] = eR*(d0*S0 + d3*S3) + 2.f*(e1r*S1r - e1i*S1i);
        }

        // ---- update: M <- M · diag(d_{wi+1}) · circ(B_{wi+1}) ----
        {
            const float* Bp = WS + 64 + 4*(wi+1);
            const float C0n=Bp[0], C3n=Bp[1], CRn=Bp[2], CIn=Bp[3]; // C1 = CR - i*CI
            // row 0
            float n0 = a0*d0, n3 = a3*d3;
            float n1r = a1r*mr - a1i*mi, n1i = a1r*mi + a1i*mr;
            a0  = n0*C0n + n3*C3n + 2.f*(n1r*CRn + n1i*CIn);
            a3  = n0*C3n + n3*C0n + 2.f*(n1r*CRn - n1i*CIn);
            a1r = (n0+n3)*CRn + n1r*(C0n+C3n);
            a1i = (n3-n0)*CIn + n1i*(C0n-C3n);
            // row 3
            float p0 = c0*d0, p3 = c3*d3;
            float p1r = c1r*mr - c1i*mi, p1i = c1r*mi + c1i*mr;
            c0  = p0*C0n + p3*C3n + 2.f*(p1r*CRn + p1i*CIn);
            c3  = p0*C3n + p3*C0n + 2.f*(p1r*CRn - p1i*CIn);
            c1r = (p0+p3)*CRn + p1r*(C0n+C3n);
            c1i = (p3-p0)*CIn + p1i*(C0n-C3n);
            // row 1
            float q0r = b0r*d0, q0i = b0i*d0;
            float q1r = b1r*mr - b1i*mi, q1i = b1r*mi + b1i*mr;
            float q2r = b2r*mr + b2i*mi, q2i = b2i*mr - b2r*mi;
            float q3r = b3r*d3, q3i = b3i*d3;
            float nb0r = q0r*C0n + q1r*CRn + q1i*CIn + q2r*CRn - q2i*CIn + q3r*C3n;
            float nb0i = q0i*C0n + q1i*CRn - q1r*CIn + q2i*CRn + q2r*CIn + q3i*C3n;
            float nb1r = q0r*CRn + q0i*CIn + q1r*C0n + q2r*C3n + q3r*CRn - q3i*CIn;
            float nb1i = q0i*CRn - q0r*CIn + q1i*C0n + q2i*C3n + q3i*CRn + q3r*CIn;
            float nb2r = q0r*CRn - q0i*CIn + q1r*C3n + q2r*C0n + q3r*CRn + q3i*CIn;
            float nb2i = q0i*CRn + q0r*CIn + q1i*C3n + q2i*C0n + q3i*CRn - q3r*CIn;
            float nb3r = q0r*C3n + q1r*CRn - q1i*CIn + q2r*CRn + q2i*CIn + q3r*C0n;
            float nb3i = q0i*C3n + q1i*CRn + q1r*CIn + q2i*CRn - q2r*CIn + q3i*C0n;
            b0r=nb0r; b0i=nb0i; b1r=nb1r; b1i=nb1i;
            b2r=nb2r; b2i=nb2i; b3r=nb3r; b3i=nb3i;
        }
    }

    // ---- final closures from M = sites 1..7 ----
    {
        float Q0 = a0*G00 + c0*G11 + 2.f*(b0r*G01r - b0i*G01i);
        float Q3 = a3*G11 + c3*G00 + 2.f*(b3r*G01r + b3i*G01i);
        float Q1r = a1r*G01r - a1i*G01i + b1r*G00 + b2r*G11 + c1r*G01r + c1i*G01i;
        float Q1i = a1r*G01i + a1i*G01r + b1i*G00 - b2i*G11 + c1i*G01r - c1r*G01i;
        o[7] = B00*Q0 + B11*Q3 + 2.f*(BR0*Q1r + BI0*Q1i);
        o[0] = 0.5f*(Q0 + Q3);
    }
}

// One wave64 per batch row: h = qf_row @ W1 + b1 ; LayerNorm ; ReLU ; sigmoid(h @ W2 + b2)
__global__ __launch_bounds__(256) void head_kernel(const float* __restrict__ qf,
                                                   const float* __restrict__ W1,
                                                   const float* __restrict__ b1v,
                                                   const float* __restrict__ gam,
                                                   const float* __restrict__ bet,
                                                   const float* __restrict__ W2,
                                                   const float* __restrict__ b2v,
                                                   float* __restrict__ score) {
    const int lane = threadIdx.x & 63;
    int b = (blockIdx.x << 2) + (threadIdx.x >> 6);
    b = __builtin_amdgcn_readfirstlane(b);
    const float* row = qf + b * (T_ * D_);
    float h = b1v[lane];
#pragma unroll
    for (int k4 = 0; k4 < (T_ * D_) / 4; ++k4) {
        float4 rv = *(const float4*)(row + 4*k4);
        h = fmaf(rv.x, W1[((4*k4+0) << 6) + lane], h);
        h = fmaf(rv.y, W1[((4*k4+1) << 6) + lane], h);
        h = fmaf(rv.z, W1[((4*k4+2) << 6) + lane], h);
        h = fmaf(rv.w, W1[((4*k4+3) << 6) + lane], h);
    }
    float t = h;
#pragma unroll
    for (int m = 1; m < 64; m <<= 1) t += __shfl_xor(t, m, 64);
    float mu = t * (1.0f / 64.0f);
    float d = h - mu;
    float vv = d * d;
#pragma unroll
    for (int m = 1; m < 64; m <<= 1) vv += __shfl_xor(vv, m, 64);
    float rs = rsqrtf(vv * (1.0f / 64.0f) + 1e-5f);
    float hn = fmaxf(d * rs * gam[lane] + bet[lane], 0.f);
    float sacc = hn * W2[lane];
#pragma unroll
    for (int m = 1; m < 64; m <<= 1) sacc += __shfl_xor(sacc, m, 64);
    if (lane == 0) score[b] = 1.0f / (1.0f + expf(-(sacc + b2v[0])));
}

extern "C" void kernel_launch(void* const* d_in, const int* in_sizes, int n_in,
                              void* d_out, int out_size, void* d_ws, size_t ws_size,
                              hipStream_t stream) {
    const float* X_seq  = (const float*)d_in[0];
    const float* params = (const float*)d_in[1];
    const float* W1     = (const float*)d_in[2];
    const float* b1v    = (const float*)d_in[3];
    const float* gam    = (const float*)d_in[4];
    const float* bet    = (const float*)d_in[5];
    const float* W2     = (const float*)d_in[6];
    const float* b2v    = (const float*)d_in[7];

    float* out   = (float*)d_out;
    float* score = out;          // B floats
    float* qf    = out + B_;     // B*T*D floats
    float* WS    = (float*)d_ws; // 96 floats

    hipLaunchKernelGGL(precompute_U, dim3(1), dim3(64), 0, stream, params, WS);
    hipLaunchKernelGGL(sim_kernel, dim3(NSAMP / 256), dim3(256), 0, stream, X_seq, WS, qf);
    hipLaunchKernelGGL(head_kernel, dim3(B_ / 4), dim3(256), 0, stream,
                       qf, W1, b1v, gam, bet, W2, b2v, score);
}